// Round 3
// baseline (266.486 us; speedup 1.0000x reference)
//
#include <hip/hip_runtime.h>
#include <hip/hip_bf16.h>
#include <cstdint>

typedef __bf16 bf16;
typedef __bf16 bf16x8 __attribute__((ext_vector_type(8)));
typedef __bf16 bf16x4 __attribute__((ext_vector_type(4)));
typedef float f32x4 __attribute__((ext_vector_type(4)));

__device__ inline bf16x8 cvt8(const float* __restrict__ p) {
  float4 a = *(const float4*)p;
  float4 b = *(const float4*)(p + 4);
  bf16x8 r;
  r[0] = (bf16)a.x; r[1] = (bf16)a.y; r[2] = (bf16)a.z; r[3] = (bf16)a.w;
  r[4] = (bf16)b.x; r[5] = (bf16)b.y; r[6] = (bf16)b.z; r[7] = (bf16)b.w;
  return r;
}

// async global->LDS, 16B per lane; LDS dest = wave-uniform base + lane*16 (m97/m104)
__device__ inline void gl_lds16(const bf16* g, bf16* l) {
  auto gp = reinterpret_cast<const __attribute__((address_space(1))) uint32_t*>(
      reinterpret_cast<uintptr_t>(g));
  auto lp = reinterpret_cast<__attribute__((address_space(3))) uint32_t*>(
      reinterpret_cast<uintptr_t>(l));
  __builtin_amdgcn_global_load_lds(gp, lp, 16, 0, 0);
}

#define BAR() asm volatile("s_barrier" ::: "memory")

// ---------------------------------------------------------------- fp32 -> bf16 cast
__global__ __launch_bounds__(256) void cast_k(const float* __restrict__ in,
                                              bf16* __restrict__ out) {
  long i = ((long)blockIdx.x * 256 + threadIdx.x) * 8;
  *(bf16x8*)(out + i) = cvt8(in + i);
}

// ---------------------------------------------------------------- transpose + fp32->bf16 cast
__global__ __launch_bounds__(256) void transpose_cast_k(const float* __restrict__ in,
                                                        bf16* __restrict__ out,
                                                        int R, int C) {
  __shared__ bf16 T[32][33];
  int tc = blockIdx.x * 32, tr = blockIdx.y * 32;
  int c = threadIdx.x & 31, r8 = threadIdx.x >> 5;
#pragma unroll
  for (int i = 0; i < 4; i++) {
    int r = r8 + i * 8;
    T[r][c] = (bf16)in[(long)(tr + r) * C + tc + c];
  }
  __syncthreads();
#pragma unroll
  for (int i = 0; i < 4; i++) {
    int r = r8 + i * 8;
    out[(long)(tc + r) * R + tr + c] = T[c][r];
  }
}

// ---------------------------------------------------------------- 256x256 8-phase QKV GEMM
// r3: deep prefetch — ALL 8 stage loads for tile kt+1 issued at phase 0 of iter kt,
// vmcnt(8) waits tile kt (full-iteration latency cover, ~8 phases vs r2's ~1 phase).
// Raw s_barrier (no vmcnt drain), XOR-swizzled LDS via pre-swizzled global source
// (rule 21), setprio around each 16-MFMA cluster. Epilogue fuses bias+RMSNorm+RoPE+l2
// for q/k (q folds cos-sim scale 8) and v -> v4(bh, tok/4, d, tok%4) layout.
__global__ __launch_bounds__(512, 2) void gemm256(const bf16* __restrict__ A,
                                                  const bf16* __restrict__ Bt,
                                                  const float* __restrict__ bias,
                                                  int K,
                                                  bf16* __restrict__ qb,
                                                  bf16* __restrict__ kb,
                                                  bf16* __restrict__ v4,
                                                  const float* __restrict__ qg,
                                                  const float* __restrict__ kg) {
  __shared__ __align__(16) bf16 As[2][16384];  // [buf][256 rows][64 cols] swizzled
  __shared__ __align__(16) bf16 Bs[2][16384];

  const int tid = threadIdx.x;
  const int lane = tid & 63;
  const int w = tid >> 6;
  const int quad = lane >> 4;
  const int l16 = lane & 15;
  const int wr = w >> 2;  // 0..1  (M half)
  const int wc = w & 3;   // 0..3  (N quarter)

  // bijective XCD swizzle (nwg = 384, %8 == 0)
  const int gx = gridDim.x;
  const int bid = blockIdx.y * gx + blockIdx.x;
  const int cpx = (gx * gridDim.y) >> 3;
  const int sw = (bid & 7) * cpx + (bid >> 3);
  const int n0 = (sw % gx) * 256;
  const int m0 = (sw / gx) * 256;

  // staging: slot s = l*512+tid; row = s>>3; physical 16B-chunk s&7 holds logical
  // chunk (s&7)^(row&7) -> pre-swizzled global source, linear LDS dest (rule 21)
  int srow[2], scof[2];
#pragma unroll
  for (int l = 0; l < 2; l++) {
    int s = l * 512 + tid;
    srow[l] = s >> 3;
    scof[l] = ((s & 7) ^ ((s >> 3) & 7)) * 8;
  }
  const bf16* aB0 = A + (long)(m0 + srow[0]) * K + scof[0];
  const bf16* aB1 = A + (long)(m0 + srow[1]) * K + scof[1];
  const bf16* bB0 = Bt + (long)(n0 + srow[0]) * K + scof[0];
  const bf16* bB1 = Bt + (long)(n0 + srow[1]) * K + scof[1];

#define STAGE_A(tb, kt1, h)                                                        \
  {                                                                                \
    gl_lds16(aB0 + (long)(h)*128 * K + (long)(kt1)*64, &As[tb][(h)*8192 + w * 512]); \
    gl_lds16(aB1 + (long)(h)*128 * K + (long)(kt1)*64,                             \
             &As[tb][(h)*8192 + 4096 + w * 512]);                                  \
  }
#define STAGE_B(tb, kt1, h)                                                        \
  {                                                                                \
    gl_lds16(bB0 + (long)(h)*128 * K + (long)(kt1)*64, &Bs[tb][(h)*8192 + w * 512]); \
    gl_lds16(bB1 + (long)(h)*128 * K + (long)(kt1)*64,                             \
             &Bs[tb][(h)*8192 + 4096 + w * 512]);                                  \
  }

  // fragment read offsets: row*64 + (clog ^ (row&7))*8 ; row&7 == l16&7
  const int cq0 = ((quad) ^ (l16 & 7)) * 8;
  const int cq1 = ((4 + quad) ^ (l16 & 7)) * 8;
  const int aoff = wr * 8192 + l16 * 64;
  const int boff = wc * 4096 + l16 * 64;

  f32x4 acc[8][4];
#pragma unroll
  for (int i = 0; i < 8; i++)
#pragma unroll
    for (int j = 0; j < 4; j++) acc[i][j] = f32x4{0.f, 0.f, 0.f, 0.f};

#define MM16(MLO, AF, BF)                                                         \
  __builtin_amdgcn_s_setprio(1);                                                  \
  _Pragma("unroll") for (int mm = 0; mm < 4; mm++)                                \
      _Pragma("unroll") for (int nn = 0; nn < 4; nn++) acc[(MLO) + mm][nn] =      \
          __builtin_amdgcn_mfma_f32_16x16x32_bf16(AF[mm], BF[nn],                 \
                                                  acc[(MLO) + mm][nn], 0, 0, 0);  \
  __builtin_amdgcn_s_setprio(0);

  const int NK = K >> 6;
  STAGE_A(0, 0, 0); STAGE_A(0, 0, 1); STAGE_B(0, 0, 0); STAGE_B(0, 0, 1);

  for (int kt = 0; kt < NK; ++kt) {
    const int pb = kt & 1;
    const int tb = pb ^ 1;
    const bool pf = (kt + 1 < NK);
    bf16x8 afr[4], bfr[4];
    // ---- phase 0: issue ALL next-tile stages, gate tile kt, compute quadrant 0
    if (pf) {
      STAGE_A(tb, kt + 1, 0);
      STAGE_A(tb, kt + 1, 1);
      STAGE_B(tb, kt + 1, 0);
      STAGE_B(tb, kt + 1, 1);
      asm volatile("s_waitcnt vmcnt(8)" ::: "memory");  // tile kt landed, 8 in flight
    } else {
      asm volatile("s_waitcnt vmcnt(0)" ::: "memory");
    }
    BAR();
#pragma unroll
    for (int n = 0; n < 4; n++) bfr[n] = *(const bf16x8*)&Bs[pb][boff + n * 1024 + cq0];
#pragma unroll
    for (int m = 0; m < 4; m++) afr[m] = *(const bf16x8*)&As[pb][aoff + m * 1024 + cq0];
    MM16(0, afr, bfr)
    BAR();
    // ---- phase 1: A m4-7 kk0 (B kk0 frags still live)
#pragma unroll
    for (int m = 0; m < 4; m++)
      afr[m] = *(const bf16x8*)&As[pb][aoff + 4096 + m * 1024 + cq0];
    BAR();
    MM16(4, afr, bfr)
    BAR();
    // ---- phase 2: B kk1 + A m0-3 kk1
#pragma unroll
    for (int n = 0; n < 4; n++) bfr[n] = *(const bf16x8*)&Bs[pb][boff + n * 1024 + cq1];
#pragma unroll
    for (int m = 0; m < 4; m++) afr[m] = *(const bf16x8*)&As[pb][aoff + m * 1024 + cq1];
    BAR();
    MM16(0, afr, bfr)
    BAR();
    // ---- phase 3: A m4-7 kk1
#pragma unroll
    for (int m = 0; m < 4; m++)
      afr[m] = *(const bf16x8*)&As[pb][aoff + 4096 + m * 1024 + cq1];
    BAR();
    MM16(4, afr, bfr)
    BAR();
  }

  // ---------------- epilogue: frag (m,n): row m0+wr*128+m*16+quad*4+r,
  //                  col n0+wc*64+n*16+l16  (m89/m91 C layout)
  const int which = n0 >> 10;  // 0=q, 1=k, 2=v
  if (which == 2) {
    const int T0 = (((m0 & 1023) + wr * 128) >> 2) + quad;
    const int bh = (m0 >> 10) * 16 + ((n0 & 1023) >> 6) + wc;
#pragma unroll
    for (int m = 0; m < 8; m++) {
#pragma unroll
      for (int n = 0; n < 4; n++) {
        int ng = n0 + wc * 64 + n * 16 + l16;
        int dc = n * 16 + l16;
        float bj = bias[ng];
        bf16x4 pv;
#pragma unroll
        for (int r = 0; r < 4; r++) pv[r] = (bf16)(acc[m][n][r] + bj);
        *(bf16x4*)(v4 + ((long)bh * 16384 + (long)(T0 + m * 4) * 64 + dc) * 4) = pv;
      }
    }
    return;
  }

  // q/k: fused bias + RMSNorm + 2D RoPE + l2-normalize (+8x fold for q).
  const float* gg = which ? kg : qg;
  bf16* dst = which ? kb : qb;
  const float fold = which ? 1.0f : 8.0f;
  const int h = ((n0 + wc * 64) & 1023) >> 6;
  const int bh = (m0 >> 10) * 16 + h;
  float bj[4], gain[4];
#pragma unroll
  for (int j = 0; j < 4; j++) {
    bj[j] = bias[n0 + wc * 64 + j * 16 + l16];
    gain[j] = gg[j * 16 + l16];
  }
  const float f = exp2f((float)l16 * (-13.287712379549449f / 16.0f));  // 10000^(-l16/16)

#pragma unroll
  for (int m = 0; m < 8; m++) {
#pragma unroll
    for (int r = 0; r < 4; r++) {
      int ntok = (m0 & 1023) + wr * 128 + m * 16 + quad * 4 + r;
      float v0 = acc[m][0][r] + bj[0];
      float v1 = acc[m][1][r] + bj[1];
      float v2 = acc[m][2][r] + bj[2];
      float v3 = acc[m][3][r] + bj[3];
      float ss = v0 * v0 + v1 * v1 + v2 * v2 + v3 * v3;
#pragma unroll
      for (int mk = 1; mk <= 8; mk <<= 1) ss += __shfl_xor(ss, mk, 64);
      float rms = rsqrtf(ss * (1.0f / 64.0f) + 1e-6f);
      v0 *= rms * gain[0]; v1 *= rms * gain[1]; v2 *= rms * gain[2]; v3 *= rms * gain[3];
      float sh, ch_, swv, cw;
      __sincosf((float)(ntok >> 5) * f, &sh, &ch_);
      __sincosf((float)(ntok & 31) * f, &swv, &cw);
      float w0 = v0 * ch_ - v2 * sh;
      float w1 = v1 * cw - v3 * swv;
      float w2 = v2 * ch_ + v0 * sh;
      float w3 = v3 * cw + v1 * swv;
      float nn = w0 * w0 + w1 * w1 + w2 * w2 + w3 * w3;
#pragma unroll
      for (int mk = 1; mk <= 8; mk <<= 1) nn += __shfl_xor(nn, mk, 64);
      float inv = rsqrtf(nn) * fold;
      long base = ((long)bh * 1024 + ntok) * 64 + l16;
      dst[base] = (bf16)(w0 * inv);
      dst[base + 16] = (bf16)(w1 * inv);
      dst[base + 32] = (bf16)(w2 * inv);
      dst[base + 48] = (bf16)(w3 * inv);
    }
  }
}

// ---------------------------------------------------------------- out-proj GEMM (r0-proven 128^2)
// A = attention-out in (b,h,tok,d) layout (qb buffer), remapped loads; fp32 C write.
// grid (8,64) = 512 blocks = 2 blocks/CU, balanced.
__global__ __launch_bounds__(256, 5) void gemm_bt1(const bf16* __restrict__ A,
                                                   const bf16* __restrict__ Bt,
                                                   const float* __restrict__ bias,
                                                   int N, int K,
                                                   float* __restrict__ out) {
  __shared__ __align__(16) bf16 As[128][32];
  __shared__ __align__(16) bf16 Bs[128][32];

  const int tid = threadIdx.x;
  const int lane = tid & 63;
  const int w = tid >> 6;
  const int wm = (w & 1) * 64;
  const int wn = (w >> 1) * 64;
  const int quad = lane >> 4;
  const int l16 = lane & 15;

  const int m0 = blockIdx.y * 128;
  const int n0 = blockIdx.x * 128;

  const int sr = w * 32 + (lane >> 2);
  const int sc = (lane & 3) * 8;

  f32x4 acc[4][4];
#pragma unroll
  for (int i = 0; i < 4; i++)
#pragma unroll
    for (int j = 0; j < 4; j++) acc[i][j] = f32x4{0.f, 0.f, 0.f, 0.f};

  for (int k0 = 0; k0 < K; k0 += 32) {
    __syncthreads();
    int hh = k0 >> 6, dc = (k0 & 63) + sc;
    int m1 = m0 + sr, m2 = m1 + 16;
    const bf16* ga0 = A + ((long)((m1 >> 10) * 16 + hh) * 1024 + (m1 & 1023)) * 64 + dc;
    const bf16* ga1 = A + ((long)((m2 >> 10) * 16 + hh) * 1024 + (m2 & 1023)) * 64 + dc;
    gl_lds16(ga0, &As[w * 32][0]);
    gl_lds16(ga1, &As[w * 32 + 16][0]);
    gl_lds16(Bt + (long)(n0 + sr) * K + k0 + sc, &Bs[w * 32][0]);
    gl_lds16(Bt + (long)(n0 + sr + 16) * K + k0 + sc, &Bs[w * 32 + 16][0]);
    __syncthreads();

    bf16x8 af[4], bfr[4];
#pragma unroll
    for (int i = 0; i < 4; i++) {
      af[i] = *(const bf16x8*)&As[wm + i * 16 + l16][quad * 8];
      bfr[i] = *(const bf16x8*)&Bs[wn + i * 16 + l16][quad * 8];
    }
#pragma unroll
    for (int i = 0; i < 4; i++)
#pragma unroll
      for (int j = 0; j < 4; j++)
        acc[i][j] = __builtin_amdgcn_mfma_f32_16x16x32_bf16(af[i], bfr[j], acc[i][j], 0, 0, 0);
  }

#pragma unroll
  for (int i = 0; i < 4; i++)
#pragma unroll
    for (int j = 0; j < 4; j++)
#pragma unroll
      for (int r = 0; r < 4; r++) {
        int mg = m0 + wm + i * 16 + quad * 4 + r;
        int ng = n0 + wn + j * 16 + l16;
        out[(long)mg * N + ng] = acc[i][j][r] + bias[ng];
      }
}

// ---------------------------------------------------------------- flash attention (fixed-max softmax)
// r3: double-buffered K/V staging with raw barriers. Next tile's K (global->regs) and
// V (gl_lds -> alternate Vl buffer) issued BEFORE compute; vmcnt + K ds_write after the
// g-loop; ONE barrier per tile (vs two full __syncthreads drains). Staging latency
// hides under the ~16-MFMA-per-g compute. LDS 44KB -> still 2 blocks/CU.
__global__ __launch_bounds__(256, 2) void attn_k(bf16* __restrict__ qb,
                                                 const bf16* __restrict__ kb,
                                                 const bf16* __restrict__ v4) {
  __shared__ __align__(16) bf16 Ks[2][64][72];   // keys x d (padded, dbuf)
  __shared__ __align__(16) bf16 Vl[2][4096];     // linear v4 tile (dbuf)
  __shared__ __align__(16) bf16 Ps[4][16][72];   // per-wave P[q][key]

  const int tid = threadIdx.x;
  const int lane = tid & 63;
  const int w = tid >> 6;
  const int quad = lane >> 4;
  const int l16 = lane & 15;

  const int bh = blockIdx.y;
  const int q0 = blockIdx.x * 256 + w * 64;

  // Q fragments for 4 query groups (q already holds cos-sim scale 8)
  bf16x8 aq[4][2];
  long qrow[4];
#pragma unroll
  for (int g = 0; g < 4; g++) {
    qrow[g] = ((long)bh * 1024 + q0 + g * 16 + l16) * 64;
    aq[g][0] = *(const bf16x8*)(qb + qrow[g] + quad * 8);
    aq[g][1] = *(const bf16x8*)(qb + qrow[g] + 32 + quad * 8);
  }

  f32x4 o[4][4];
#pragma unroll
  for (int g = 0; g < 4; g++)
#pragma unroll
    for (int i = 0; i < 4; i++) o[g][i] = f32x4{0.f, 0.f, 0.f, 0.f};
  float ls[4] = {0.f, 0.f, 0.f, 0.f};

  const int sr = tid >> 3, sc = (tid & 7) * 8;  // K staging: 32 rows x 64 cols per load
  const bf16* kbase = kb + (long)bh * 65536;
  const bf16* vbase = v4 + (long)bh * 65536;

  // prologue: stage tile 0 into buffer 0
  bf16x8 kr0 = *(const bf16x8*)(kbase + (long)sr * 64 + sc);
  bf16x8 kr1 = *(const bf16x8*)(kbase + (long)(sr + 32) * 64 + sc);
  gl_lds16(vbase + (w * 2) * 512 + lane * 8, &Vl[0][(w * 2) * 512]);
  gl_lds16(vbase + (w * 2 + 1) * 512 + lane * 8, &Vl[0][(w * 2 + 1) * 512]);
  asm volatile("s_waitcnt vmcnt(0)" ::: "memory");
  *(bf16x8*)&Ks[0][sr][sc] = kr0;
  *(bf16x8*)&Ks[0][sr + 32][sc] = kr1;
  asm volatile("s_waitcnt lgkmcnt(0)" ::: "memory");
  BAR();

  for (int kt = 0; kt < 1024; kt += 64) {
    const int cur = (kt >> 6) & 1;
    const bool pf = (kt + 64 < 1024);
    // issue next tile's staging loads (K -> regs, V -> alternate LDS buffer)
    if (pf) {
      kr0 = *(const bf16x8*)(kbase + (long)(kt + 64 + sr) * 64 + sc);
      kr1 = *(const bf16x8*)(kbase + (long)(kt + 64 + sr + 32) * 64 + sc);
      gl_lds16(vbase + (long)(kt + 64) * 64 + (w * 2) * 512 + lane * 8,
               &Vl[cur ^ 1][(w * 2) * 512]);
      gl_lds16(vbase + (long)(kt + 64) * 64 + (w * 2 + 1) * 512 + lane * 8,
               &Vl[cur ^ 1][(w * 2 + 1) * 512]);
    }

    // hoist K-frags and V-frags for this tile
    bf16x8 kf[4][2], vf[4][2];
#pragma unroll
    for (int i = 0; i < 4; i++) {
      kf[i][0] = *(const bf16x8*)&Ks[cur][i * 16 + l16][quad * 8];
      kf[i][1] = *(const bf16x8*)&Ks[cur][i * 16 + l16][32 + quad * 8];
      int D4 = (i * 16 + l16) * 4;
      bf16x4 a0 = *(const bf16x4*)&Vl[cur][quad * 512 + D4];
      bf16x4 a1 = *(const bf16x4*)&Vl[cur][quad * 512 + D4 + 256];
      bf16x4 a2 = *(const bf16x4*)&Vl[cur][quad * 512 + D4 + 2048];
      bf16x4 a3 = *(const bf16x4*)&Vl[cur][quad * 512 + D4 + 2048 + 256];
      vf[i][0] = __builtin_shufflevector(a0, a1, 0, 1, 2, 3, 4, 5, 6, 7);
      vf[i][1] = __builtin_shufflevector(a2, a3, 0, 1, 2, 3, 4, 5, 6, 7);
    }

#pragma unroll
    for (int g = 0; g < 4; g++) {
      // St = K_tile · Qg^T ; p = exp(s-8); per-lane l partial (column q=l16)
#pragma unroll
      for (int i = 0; i < 4; i++) {
        f32x4 st = f32x4{0.f, 0.f, 0.f, 0.f};
        st = __builtin_amdgcn_mfma_f32_16x16x32_bf16(kf[i][0], aq[g][0], st, 0, 0, 0);
        st = __builtin_amdgcn_mfma_f32_16x16x32_bf16(kf[i][1], aq[g][1], st, 0, 0, 0);
        bf16x4 pk;
#pragma unroll
        for (int r = 0; r < 4; r++) {
          float p = __expf(st[r] - 8.0f);
          ls[g] += p;
          pk[r] = (bf16)p;
        }
        *(bf16x4*)&Ps[w][l16][i * 16 + quad * 4] = pk;
      }
      asm volatile("s_waitcnt lgkmcnt(0)" ::: "memory");
      bf16x8 bp0 = *(const bf16x8*)&Ps[w][l16][quad * 8];
      bf16x8 bp1 = *(const bf16x8*)&Ps[w][l16][32 + quad * 8];
#pragma unroll
      for (int i = 0; i < 4; i++) {
        o[g][i] = __builtin_amdgcn_mfma_f32_16x16x32_bf16(vf[i][0], bp0, o[g][i], 0, 0, 0);
        o[g][i] = __builtin_amdgcn_mfma_f32_16x16x32_bf16(vf[i][1], bp1, o[g][i], 0, 0, 0);
      }
    }

    // commit next tile: wait K regs + V gl_lds (covered by the g-loop), write K to LDS
    if (pf) {
      asm volatile("s_waitcnt vmcnt(0)" ::: "memory");
      *(bf16x8*)&Ks[cur ^ 1][sr][sc] = kr0;
      *(bf16x8*)&Ks[cur ^ 1][sr + 32][sc] = kr1;
    }
    asm volatile("s_waitcnt lgkmcnt(0)" ::: "memory");
    BAR();
  }

#pragma unroll
  for (int g = 0; g < 4; g++) {
    float l = ls[g];
    l += __shfl_xor(l, 16, 64);
    l += __shfl_xor(l, 32, 64);
    float inv = 1.0f / l;
#pragma unroll
    for (int i = 0; i < 4; i++) {
      bf16x4 ov;
#pragma unroll
      for (int r = 0; r < 4; r++) ov[r] = (bf16)(o[g][i][r] * inv);
      *(bf16x4*)(qb + qrow[g] + i * 16 + quad * 4) = ov;
    }
  }
}

// ---------------------------------------------------------------- launcher
extern "C" void kernel_launch(void* const* d_in, const int* in_sizes, int n_in,
                              void* d_out, int out_size, void* d_ws, size_t ws_size,
                              hipStream_t stream) {
  (void)in_sizes; (void)n_in; (void)out_size; (void)ws_size;
  const float* x     = (const float*)d_in[0];
  const float* w_qkv = (const float*)d_in[1];
  const float* b_qkv = (const float*)d_in[2];
  const float* q_g   = (const float*)d_in[3];
  const float* k_g   = (const float*)d_in[4];
  const float* w_out = (const float*)d_in[5];
  const float* b_out = (const float*)d_in[6];
  float* out = (float*)d_out;

  char* ws = (char*)d_ws;
  bf16* wqkvT = (bf16*)ws; ws += (long)3072 * 1024 * 2;      // 6 MB
  bf16* woT   = (bf16*)ws; ws += (long)1024 * 1024 * 2;      // 2 MB
  bf16* xb    = (bf16*)ws; ws += (long)8192 * 1024 * 2;      // 16 MB
  bf16* qb    = (bf16*)ws; ws += (long)128 * 1024 * 64 * 2;  // 16 MB (q, then attention O)
  bf16* kb    = (bf16*)ws; ws += (long)128 * 1024 * 64 * 2;  // 16 MB
  bf16* v4    = (bf16*)ws; ws += (long)128 * 64 * 1024 * 2;  // 16 MB   (total 72 MB)

  cast_k<<<4096, 256, 0, stream>>>(x, xb);
  transpose_cast_k<<<dim3(3072 / 32, 1024 / 32), 256, 0, stream>>>(w_qkv, wqkvT, 1024, 3072);
  transpose_cast_k<<<dim3(1024 / 32, 1024 / 32), 256, 0, stream>>>(w_out, woT, 1024, 1024);
  gemm256<<<dim3(3072 / 256, 8192 / 256), 512, 0, stream>>>(xb, wqkvT, b_qkv, 1024,
                                                            qb, kb, v4, q_g, k_g);
  attn_k<<<dim3(4, 128), 256, 0, stream>>>(qb, kb, v4);
  gemm_bt1<<<dim3(1024 / 128, 8192 / 128), 256, 0, stream>>>(qb, woT, b_out,
                                                             1024, 1024, out);
}

// Round 4
// 261.713 us; speedup vs baseline: 1.0182x; 1.0182x over previous
//
#include <hip/hip_runtime.h>
#include <hip/hip_bf16.h>
#include <cstdint>

typedef __bf16 bf16;
typedef __bf16 bf16x8 __attribute__((ext_vector_type(8)));
typedef __bf16 bf16x4 __attribute__((ext_vector_type(4)));
typedef float f32x4 __attribute__((ext_vector_type(4)));

__device__ inline bf16x8 cvt8(const float* __restrict__ p) {
  float4 a = *(const float4*)p;
  float4 b = *(const float4*)(p + 4);
  bf16x8 r;
  r[0] = (bf16)a.x; r[1] = (bf16)a.y; r[2] = (bf16)a.z; r[3] = (bf16)a.w;
  r[4] = (bf16)b.x; r[5] = (bf16)b.y; r[6] = (bf16)b.z; r[7] = (bf16)b.w;
  return r;
}

// async global->LDS, 16B per lane; LDS dest = wave-uniform base + lane*16 (m97/m104)
__device__ inline void gl_lds16(const bf16* g, bf16* l) {
  auto gp = reinterpret_cast<const __attribute__((address_space(1))) uint32_t*>(
      reinterpret_cast<uintptr_t>(g));
  auto lp = reinterpret_cast<__attribute__((address_space(3))) uint32_t*>(
      reinterpret_cast<uintptr_t>(l));
  __builtin_amdgcn_global_load_lds(gp, lp, 16, 0, 0);
}

#define BAR() asm volatile("s_barrier" ::: "memory")

// ---------------------------------------------------------------- fp32 -> bf16 cast
__global__ __launch_bounds__(256) void cast_k(const float* __restrict__ in,
                                              bf16* __restrict__ out) {
  long i = ((long)blockIdx.x * 256 + threadIdx.x) * 8;
  *(bf16x8*)(out + i) = cvt8(in + i);
}

// ---------------------------------------------------------------- transpose + fp32->bf16 cast
__global__ __launch_bounds__(256) void transpose_cast_k(const float* __restrict__ in,
                                                        bf16* __restrict__ out,
                                                        int R, int C) {
  __shared__ bf16 T[32][33];
  int tc = blockIdx.x * 32, tr = blockIdx.y * 32;
  int c = threadIdx.x & 31, r8 = threadIdx.x >> 5;
#pragma unroll
  for (int i = 0; i < 4; i++) {
    int r = r8 + i * 8;
    T[r][c] = (bf16)in[(long)(tr + r) * C + tc + c];
  }
  __syncthreads();
#pragma unroll
  for (int i = 0; i < 4; i++) {
    int r = r8 + i * 8;
    out[(long)(tc + r) * R + tr + c] = T[c][r];
  }
}

// ---------------------------------------------------------------- 128x256 QKV GEMM, 3 blocks/CU
// r4: occupancy-first redesign. Tile BM=128 BN=256 BK=32, dbuf LDS = 48KB -> 3 blocks/CU;
// grid 64x12 = 768 blocks = EXACTLY 3/CU x 256 CU, all resident, zero grid tail.
// Inter-block wave overlap (m114) hides barrier/ds_read stalls that the 1-block/CU
// 8-phase template could not. Simple loop: stage(kt+1) -> counted vmcnt(3) gate ->
// raw s_barrier (no drain) -> 8 ds_read_b128 -> 16 MFMA (setprio) -> barrier.
// XOR swizzle for BK=32 (4x16B chunks/row): phys = c ^ ((row>>1)&3) -> 2-way/free.
// 8 waves 2Mx4N, per-wave 64x64 out (acc[4][4] = 64 AGPR, ~112 total regs).
// Epilogue fuses bias+RMSNorm+RoPE+l2 for q/k (q folds cos-sim scale 8), v -> v4 layout.
__global__ __launch_bounds__(512, 4) void gemm256(const bf16* __restrict__ A,
                                                  const bf16* __restrict__ Bt,
                                                  const float* __restrict__ bias,
                                                  int K,
                                                  bf16* __restrict__ qb,
                                                  bf16* __restrict__ kb,
                                                  bf16* __restrict__ v4,
                                                  const float* __restrict__ qg,
                                                  const float* __restrict__ kg) {
  __shared__ __align__(16) bf16 As[2][4096];  // [buf][128 rows][32 cols] swizzled
  __shared__ __align__(16) bf16 Bs[2][8192];  // [buf][256 rows][32 cols] swizzled

  const int tid = threadIdx.x;
  const int lane = tid & 63;
  const int w = tid >> 6;
  const int quad = lane >> 4;
  const int l16 = lane & 15;
  const int wr = w >> 2;  // 0..1  (64-row half of BM=128)
  const int wc = w & 3;   // 0..3  (64-col quarter of BN=256)

  // bijective XCD swizzle (nwg = 768, %8 == 0)
  const int gx = gridDim.x;  // 12
  const int bid = blockIdx.y * gx + blockIdx.x;
  const int cpx = (gx * gridDim.y) >> 3;
  const int sw = (bid & 7) * cpx + (bid >> 3);
  const int n0 = (sw % gx) * 256;
  const int m0 = (sw / gx) * 128;

  // staging: slot s -> row r = s>>2, phys 16B-chunk p = s&3 holds logical chunk
  // c = p ^ ((r>>1)&3)  (pre-swizzled global source, linear LDS dest; rule 21)
  const int srA = tid >> 2;                       // 0..127
  const int scS = ((tid & 3) ^ ((tid >> 3) & 3)) * 8;
  const bf16* aS = A + (long)(m0 + srA) * K + scS;
  const bf16* bS0 = Bt + (long)(n0 + srA) * K + scS;        // rows 0..127
  const bf16* bS1 = bS0 + (long)128 * K;                    // rows 128..255

#define STAGE(tb, kt1)                                                   \
  {                                                                      \
    const long kc = (long)(kt1)*32;                                      \
    gl_lds16(aS + kc, &As[tb][w * 512]);                                 \
    gl_lds16(bS0 + kc, &Bs[tb][w * 512]);                                \
    gl_lds16(bS1 + kc, &Bs[tb][4096 + w * 512]);                         \
  }

  // fragment reads: row*32 + (quad ^ ((l16>>1)&3))*8  (row base mult of 16)
  const int cphys = (quad ^ ((l16 >> 1) & 3)) * 8;
  const int aoff = (wr * 64 + l16) * 32 + cphys;
  const int boff = (wc * 64 + l16) * 32 + cphys;

  f32x4 acc[4][4];
#pragma unroll
  for (int i = 0; i < 4; i++)
#pragma unroll
    for (int j = 0; j < 4; j++) acc[i][j] = f32x4{0.f, 0.f, 0.f, 0.f};

  const int NK = K >> 5;  // 32
  STAGE(0, 0);

  for (int kt = 0; kt < NK; ++kt) {
    const int pb = kt & 1;
    const int tb = pb ^ 1;
    const bool pf = (kt + 1 < NK);
    if (pf) {
      STAGE(tb, kt + 1);
      asm volatile("s_waitcnt vmcnt(3)" ::: "memory");  // tile kt landed, 3 in flight
    } else {
      asm volatile("s_waitcnt vmcnt(0)" ::: "memory");
    }
    BAR();
    bf16x8 afr[4], bfr[4];
#pragma unroll
    for (int n = 0; n < 4; n++) bfr[n] = *(const bf16x8*)&Bs[pb][boff + n * 512];
#pragma unroll
    for (int m = 0; m < 4; m++) afr[m] = *(const bf16x8*)&As[pb][aoff + m * 512];
    __builtin_amdgcn_s_setprio(1);
#pragma unroll
    for (int m = 0; m < 4; m++)
#pragma unroll
      for (int n = 0; n < 4; n++)
        acc[m][n] = __builtin_amdgcn_mfma_f32_16x16x32_bf16(afr[m], bfr[n], acc[m][n], 0, 0, 0);
    __builtin_amdgcn_s_setprio(0);
    BAR();  // all waves done reading buf pb -> next iter may restage it
  }

  // ---------------- epilogue: frag (m,n): row m0+wr*64+m*16+quad*4+r,
  //                  col n0+wc*64+n*16+l16  (m89/m91 C layout)
  const int which = n0 >> 10;  // 0=q, 1=k, 2=v
  if (which == 2) {
    const int T0 = (((m0 & 1023) + wr * 64) >> 2) + quad;
    const int bh = (m0 >> 10) * 16 + (((n0 + wc * 64) & 1023) >> 6);
#pragma unroll
    for (int m = 0; m < 4; m++) {
#pragma unroll
      for (int n = 0; n < 4; n++) {
        int ng = n0 + wc * 64 + n * 16 + l16;
        int dc = n * 16 + l16;
        float bj = bias[ng];
        bf16x4 pv;
#pragma unroll
        for (int r = 0; r < 4; r++) pv[r] = (bf16)(acc[m][n][r] + bj);
        *(bf16x4*)(v4 + ((long)bh * 16384 + (long)(T0 + m * 4) * 64 + dc) * 4) = pv;
      }
    }
    return;
  }

  // q/k: fused bias + RMSNorm + 2D RoPE + l2-normalize (+8x fold for q).
  const float* gg = which ? kg : qg;
  bf16* dst = which ? kb : qb;
  const float fold = which ? 1.0f : 8.0f;
  const int h = ((n0 + wc * 64) & 1023) >> 6;
  const int bh = (m0 >> 10) * 16 + h;
  float bj[4], gain[4];
#pragma unroll
  for (int j = 0; j < 4; j++) {
    bj[j] = bias[n0 + wc * 64 + j * 16 + l16];
    gain[j] = gg[j * 16 + l16];
  }
  const float f = exp2f((float)l16 * (-13.287712379549449f / 16.0f));  // 10000^(-l16/16)

#pragma unroll
  for (int m = 0; m < 4; m++) {
#pragma unroll
    for (int r = 0; r < 4; r++) {
      int ntok = (m0 & 1023) + wr * 64 + m * 16 + quad * 4 + r;
      float v0 = acc[m][0][r] + bj[0];
      float v1 = acc[m][1][r] + bj[1];
      float v2 = acc[m][2][r] + bj[2];
      float v3 = acc[m][3][r] + bj[3];
      float ss = v0 * v0 + v1 * v1 + v2 * v2 + v3 * v3;
#pragma unroll
      for (int mk = 1; mk <= 8; mk <<= 1) ss += __shfl_xor(ss, mk, 64);
      float rms = rsqrtf(ss * (1.0f / 64.0f) + 1e-6f);
      v0 *= rms * gain[0]; v1 *= rms * gain[1]; v2 *= rms * gain[2]; v3 *= rms * gain[3];
      float sh, ch_, swv, cw;
      __sincosf((float)(ntok >> 5) * f, &sh, &ch_);
      __sincosf((float)(ntok & 31) * f, &swv, &cw);
      float w0 = v0 * ch_ - v2 * sh;
      float w1 = v1 * cw - v3 * swv;
      float w2 = v2 * ch_ + v0 * sh;
      float w3 = v3 * cw + v1 * swv;
      float nn = w0 * w0 + w1 * w1 + w2 * w2 + w3 * w3;
#pragma unroll
      for (int mk = 1; mk <= 8; mk <<= 1) nn += __shfl_xor(nn, mk, 64);
      float inv = rsqrtf(nn) * fold;
      long base = ((long)bh * 1024 + ntok) * 64 + l16;
      dst[base] = (bf16)(w0 * inv);
      dst[base + 16] = (bf16)(w1 * inv);
      dst[base + 32] = (bf16)(w2 * inv);
      dst[base + 48] = (bf16)(w3 * inv);
    }
  }
}

// ---------------------------------------------------------------- out-proj GEMM (r0-proven 128^2)
// A = attention-out in (b,h,tok,d) layout (qb buffer), remapped loads; fp32 C write.
// grid (8,64) = 512 blocks = 2-3 blocks/CU, balanced.
__global__ __launch_bounds__(256, 5) void gemm_bt1(const bf16* __restrict__ A,
                                                   const bf16* __restrict__ Bt,
                                                   const float* __restrict__ bias,
                                                   int N, int K,
                                                   float* __restrict__ out) {
  __shared__ __align__(16) bf16 As[128][32];
  __shared__ __align__(16) bf16 Bs[128][32];

  const int tid = threadIdx.x;
  const int lane = tid & 63;
  const int w = tid >> 6;
  const int wm = (w & 1) * 64;
  const int wn = (w >> 1) * 64;
  const int quad = lane >> 4;
  const int l16 = lane & 15;

  const int m0 = blockIdx.y * 128;
  const int n0 = blockIdx.x * 128;

  const int sr = w * 32 + (lane >> 2);
  const int sc = (lane & 3) * 8;

  f32x4 acc[4][4];
#pragma unroll
  for (int i = 0; i < 4; i++)
#pragma unroll
    for (int j = 0; j < 4; j++) acc[i][j] = f32x4{0.f, 0.f, 0.f, 0.f};

  for (int k0 = 0; k0 < K; k0 += 32) {
    __syncthreads();
    int hh = k0 >> 6, dc = (k0 & 63) + sc;
    int m1 = m0 + sr, m2 = m1 + 16;
    const bf16* ga0 = A + ((long)((m1 >> 10) * 16 + hh) * 1024 + (m1 & 1023)) * 64 + dc;
    const bf16* ga1 = A + ((long)((m2 >> 10) * 16 + hh) * 1024 + (m2 & 1023)) * 64 + dc;
    gl_lds16(ga0, &As[w * 32][0]);
    gl_lds16(ga1, &As[w * 32 + 16][0]);
    gl_lds16(Bt + (long)(n0 + sr) * K + k0 + sc, &Bs[w * 32][0]);
    gl_lds16(Bt + (long)(n0 + sr + 16) * K + k0 + sc, &Bs[w * 32 + 16][0]);
    __syncthreads();

    bf16x8 af[4], bfr[4];
#pragma unroll
    for (int i = 0; i < 4; i++) {
      af[i] = *(const bf16x8*)&As[wm + i * 16 + l16][quad * 8];
      bfr[i] = *(const bf16x8*)&Bs[wn + i * 16 + l16][quad * 8];
    }
#pragma unroll
    for (int i = 0; i < 4; i++)
#pragma unroll
      for (int j = 0; j < 4; j++)
        acc[i][j] = __builtin_amdgcn_mfma_f32_16x16x32_bf16(af[i], bfr[j], acc[i][j], 0, 0, 0);
  }

#pragma unroll
  for (int i = 0; i < 4; i++)
#pragma unroll
    for (int j = 0; j < 4; j++)
#pragma unroll
      for (int r = 0; r < 4; r++) {
        int mg = m0 + wm + i * 16 + quad * 4 + r;
        int ng = n0 + wn + j * 16 + l16;
        out[(long)mg * N + ng] = acc[i][j][r] + bias[ng];
      }
}

// ---------------------------------------------------------------- flash attention (fixed-max softmax)
// r3 structure: double-buffered K/V staging with raw barriers; next tile's K (->regs)
// and V (gl_lds -> alternate buffer) issued BEFORE compute; one barrier per tile.
__global__ __launch_bounds__(256, 2) void attn_k(bf16* __restrict__ qb,
                                                 const bf16* __restrict__ kb,
                                                 const bf16* __restrict__ v4) {
  __shared__ __align__(16) bf16 Ks[2][64][72];   // keys x d (padded, dbuf)
  __shared__ __align__(16) bf16 Vl[2][4096];     // linear v4 tile (dbuf)
  __shared__ __align__(16) bf16 Ps[4][16][72];   // per-wave P[q][key]

  const int tid = threadIdx.x;
  const int lane = tid & 63;
  const int w = tid >> 6;
  const int quad = lane >> 4;
  const int l16 = lane & 15;

  const int bh = blockIdx.y;
  const int q0 = blockIdx.x * 256 + w * 64;

  // Q fragments for 4 query groups (q already holds cos-sim scale 8)
  bf16x8 aq[4][2];
  long qrow[4];
#pragma unroll
  for (int g = 0; g < 4; g++) {
    qrow[g] = ((long)bh * 1024 + q0 + g * 16 + l16) * 64;
    aq[g][0] = *(const bf16x8*)(qb + qrow[g] + quad * 8);
    aq[g][1] = *(const bf16x8*)(qb + qrow[g] + 32 + quad * 8);
  }

  f32x4 o[4][4];
#pragma unroll
  for (int g = 0; g < 4; g++)
#pragma unroll
    for (int i = 0; i < 4; i++) o[g][i] = f32x4{0.f, 0.f, 0.f, 0.f};
  float ls[4] = {0.f, 0.f, 0.f, 0.f};

  const int sr = tid >> 3, sc = (tid & 7) * 8;  // K staging: 32 rows x 64 cols per load
  const bf16* kbase = kb + (long)bh * 65536;
  const bf16* vbase = v4 + (long)bh * 65536;

  // prologue: stage tile 0 into buffer 0
  bf16x8 kr0 = *(const bf16x8*)(kbase + (long)sr * 64 + sc);
  bf16x8 kr1 = *(const bf16x8*)(kbase + (long)(sr + 32) * 64 + sc);
  gl_lds16(vbase + (w * 2) * 512 + lane * 8, &Vl[0][(w * 2) * 512]);
  gl_lds16(vbase + (w * 2 + 1) * 512 + lane * 8, &Vl[0][(w * 2 + 1) * 512]);
  asm volatile("s_waitcnt vmcnt(0)" ::: "memory");
  *(bf16x8*)&Ks[0][sr][sc] = kr0;
  *(bf16x8*)&Ks[0][sr + 32][sc] = kr1;
  asm volatile("s_waitcnt lgkmcnt(0)" ::: "memory");
  BAR();

  for (int kt = 0; kt < 1024; kt += 64) {
    const int cur = (kt >> 6) & 1;
    const bool pf = (kt + 64 < 1024);
    // issue next tile's staging loads (K -> regs, V -> alternate LDS buffer)
    if (pf) {
      kr0 = *(const bf16x8*)(kbase + (long)(kt + 64 + sr) * 64 + sc);
      kr1 = *(const bf16x8*)(kbase + (long)(kt + 64 + sr + 32) * 64 + sc);
      gl_lds16(vbase + (long)(kt + 64) * 64 + (w * 2) * 512 + lane * 8,
               &Vl[cur ^ 1][(w * 2) * 512]);
      gl_lds16(vbase + (long)(kt + 64) * 64 + (w * 2 + 1) * 512 + lane * 8,
               &Vl[cur ^ 1][(w * 2 + 1) * 512]);
    }

    // hoist K-frags and V-frags for this tile
    bf16x8 kf[4][2], vf[4][2];
#pragma unroll
    for (int i = 0; i < 4; i++) {
      kf[i][0] = *(const bf16x8*)&Ks[cur][i * 16 + l16][quad * 8];
      kf[i][1] = *(const bf16x8*)&Ks[cur][i * 16 + l16][32 + quad * 8];
      int D4 = (i * 16 + l16) * 4;
      bf16x4 a0 = *(const bf16x4*)&Vl[cur][quad * 512 + D4];
      bf16x4 a1 = *(const bf16x4*)&Vl[cur][quad * 512 + D4 + 256];
      bf16x4 a2 = *(const bf16x4*)&Vl[cur][quad * 512 + D4 + 2048];
      bf16x4 a3 = *(const bf16x4*)&Vl[cur][quad * 512 + D4 + 2048 + 256];
      vf[i][0] = __builtin_shufflevector(a0, a1, 0, 1, 2, 3, 4, 5, 6, 7);
      vf[i][1] = __builtin_shufflevector(a2, a3, 0, 1, 2, 3, 4, 5, 6, 7);
    }

#pragma unroll
    for (int g = 0; g < 4; g++) {
      // St = K_tile · Qg^T ; p = exp(s-8); per-lane l partial (column q=l16)
#pragma unroll
      for (int i = 0; i < 4; i++) {
        f32x4 st = f32x4{0.f, 0.f, 0.f, 0.f};
        st = __builtin_amdgcn_mfma_f32_16x16x32_bf16(kf[i][0], aq[g][0], st, 0, 0, 0);
        st = __builtin_amdgcn_mfma_f32_16x16x32_bf16(kf[i][1], aq[g][1], st, 0, 0, 0);
        bf16x4 pk;
#pragma unroll
        for (int r = 0; r < 4; r++) {
          float p = __expf(st[r] - 8.0f);
          ls[g] += p;
          pk[r] = (bf16)p;
        }
        *(bf16x4*)&Ps[w][l16][i * 16 + quad * 4] = pk;
      }
      asm volatile("s_waitcnt lgkmcnt(0)" ::: "memory");
      bf16x8 bp0 = *(const bf16x8*)&Ps[w][l16][quad * 8];
      bf16x8 bp1 = *(const bf16x8*)&Ps[w][l16][32 + quad * 8];
#pragma unroll
      for (int i = 0; i < 4; i++) {
        o[g][i] = __builtin_amdgcn_mfma_f32_16x16x32_bf16(vf[i][0], bp0, o[g][i], 0, 0, 0);
        o[g][i] = __builtin_amdgcn_mfma_f32_16x16x32_bf16(vf[i][1], bp1, o[g][i], 0, 0, 0);
      }
    }

    // commit next tile: wait K regs + V gl_lds (covered by the g-loop), write K to LDS
    if (pf) {
      asm volatile("s_waitcnt vmcnt(0)" ::: "memory");
      *(bf16x8*)&Ks[cur ^ 1][sr][sc] = kr0;
      *(bf16x8*)&Ks[cur ^ 1][sr + 32][sc] = kr1;
    }
    asm volatile("s_waitcnt lgkmcnt(0)" ::: "memory");
    BAR();
  }

#pragma unroll
  for (int g = 0; g < 4; g++) {
    float l = ls[g];
    l += __shfl_xor(l, 16, 64);
    l += __shfl_xor(l, 32, 64);
    float inv = 1.0f / l;
#pragma unroll
    for (int i = 0; i < 4; i++) {
      bf16x4 ov;
#pragma unroll
      for (int r = 0; r < 4; r++) ov[r] = (bf16)(o[g][i][r] * inv);
      *(bf16x4*)(qb + qrow[g] + i * 16 + quad * 4) = ov;
    }
  }
}

// ---------------------------------------------------------------- launcher
extern "C" void kernel_launch(void* const* d_in, const int* in_sizes, int n_in,
                              void* d_out, int out_size, void* d_ws, size_t ws_size,
                              hipStream_t stream) {
  (void)in_sizes; (void)n_in; (void)out_size; (void)ws_size;
  const float* x     = (const float*)d_in[0];
  const float* w_qkv = (const float*)d_in[1];
  const float* b_qkv = (const float*)d_in[2];
  const float* q_g   = (const float*)d_in[3];
  const float* k_g   = (const float*)d_in[4];
  const float* w_out = (const float*)d_in[5];
  const float* b_out = (const float*)d_in[6];
  float* out = (float*)d_out;

  char* ws = (char*)d_ws;
  bf16* wqkvT = (bf16*)ws; ws += (long)3072 * 1024 * 2;      // 6 MB
  bf16* woT   = (bf16*)ws; ws += (long)1024 * 1024 * 2;      // 2 MB
  bf16* xb    = (bf16*)ws; ws += (long)8192 * 1024 * 2;      // 16 MB
  bf16* qb    = (bf16*)ws; ws += (long)128 * 1024 * 64 * 2;  // 16 MB (q, then attention O)
  bf16* kb    = (bf16*)ws; ws += (long)128 * 1024 * 64 * 2;  // 16 MB
  bf16* v4    = (bf16*)ws; ws += (long)128 * 64 * 1024 * 2;  // 16 MB   (total 72 MB)

  cast_k<<<4096, 256, 0, stream>>>(x, xb);
  transpose_cast_k<<<dim3(3072 / 32, 1024 / 32), 256, 0, stream>>>(w_qkv, wqkvT, 1024, 3072);
  transpose_cast_k<<<dim3(1024 / 32, 1024 / 32), 256, 0, stream>>>(w_out, woT, 1024, 1024);
  gemm256<<<dim3(3072 / 256, 8192 / 128), 512, 0, stream>>>(xb, wqkvT, b_qkv, 1024,
                                                            qb, kb, v4, q_g, k_g);
  attn_k<<<dim3(4, 128), 256, 0, stream>>>(qb, kb, v4);
  gemm_bt1<<<dim3(1024 / 128, 8192 / 128), 256, 0, stream>>>(qb, woT, b_out,
                                                             1024, 1024, out);
}

// Round 5
// 245.975 us; speedup vs baseline: 1.0834x; 1.0640x over previous
//
#include <hip/hip_runtime.h>
#include <hip/hip_bf16.h>
#include <cstdint>

typedef __bf16 bf16;
typedef __bf16 bf16x8 __attribute__((ext_vector_type(8)));
typedef __bf16 bf16x4 __attribute__((ext_vector_type(4)));
typedef float f32x4 __attribute__((ext_vector_type(4)));

__device__ inline bf16x8 cvt8(const float* __restrict__ p) {
  float4 a = *(const float4*)p;
  float4 b = *(const float4*)(p + 4);
  bf16x8 r;
  r[0] = (bf16)a.x; r[1] = (bf16)a.y; r[2] = (bf16)a.z; r[3] = (bf16)a.w;
  r[4] = (bf16)b.x; r[5] = (bf16)b.y; r[6] = (bf16)b.z; r[7] = (bf16)b.w;
  return r;
}

// async global->LDS, 16B per lane; LDS dest = wave-uniform base + lane*16 (m97/m104)
__device__ inline void gl_lds16(const bf16* g, bf16* l) {
  auto gp = reinterpret_cast<const __attribute__((address_space(1))) uint32_t*>(
      reinterpret_cast<uintptr_t>(g));
  auto lp = reinterpret_cast<__attribute__((address_space(3))) uint32_t*>(
      reinterpret_cast<uintptr_t>(l));
  __builtin_amdgcn_global_load_lds(gp, lp, 16, 0, 0);
}

#define BAR() asm volatile("s_barrier" ::: "memory")

// ---------------------------------------------------------------- fused prep:
// blocks [0,4096): fp32->bf16 cast of x
// blocks [4096,7168): transpose+cast w_qkv (1024x3072 -> 3072x1024)
// blocks [7168,8192): transpose+cast w_out (1024x1024 -> 1024x1024)
// One launch instead of three (r5: ~60us of inter-dispatch gap observed across rounds).
__global__ __launch_bounds__(256) void prep_k(const float* __restrict__ x,
                                              bf16* __restrict__ xb,
                                              const float* __restrict__ wqkv,
                                              bf16* __restrict__ wqkvT,
                                              const float* __restrict__ wo,
                                              bf16* __restrict__ woT) {
  __shared__ bf16 T[32][33];
  const int bid = blockIdx.x;
  if (bid < 4096) {
    long i = ((long)bid * 256 + threadIdx.x) * 8;
    *(bf16x8*)(xb + i) = cvt8(x + i);
    return;
  }
  const float* in;
  bf16* out;
  int R, C, bx, by;
  if (bid < 7168) {
    int t = bid - 4096;
    in = wqkv; out = wqkvT; R = 1024; C = 3072;
    bx = t % 96; by = t / 96;
  } else {
    int t = bid - 7168;
    in = wo; out = woT; R = 1024; C = 1024;
    bx = t % 32; by = t / 32;
  }
  int tc = bx * 32, tr = by * 32;
  int c = threadIdx.x & 31, r8 = threadIdx.x >> 5;
#pragma unroll
  for (int i = 0; i < 4; i++) {
    int r = r8 + i * 8;
    T[r][c] = (bf16)in[(long)(tr + r) * C + tc + c];
  }
  __syncthreads();
#pragma unroll
  for (int i = 0; i < 4; i++) {
    int r = r8 + i * 8;
    out[(long)(tc + r) * R + tr + c] = T[c][r];
  }
}

// ---------------------------------------------------------------- 128x256 QKV GEMM, 3 blocks/CU
// r4 structure (proven 694 TF): BM=128 BN=256 BK=32 dbuf, 48KB LDS, grid 768 = 3/CU
// exact, raw s_barrier + counted vmcnt(3), XOR swizzle (pre-swizzled source, rule 21).
__global__ __launch_bounds__(512, 4) void gemm256(const bf16* __restrict__ A,
                                                  const bf16* __restrict__ Bt,
                                                  const float* __restrict__ bias,
                                                  int K,
                                                  bf16* __restrict__ qb,
                                                  bf16* __restrict__ kb,
                                                  bf16* __restrict__ v4,
                                                  const float* __restrict__ qg,
                                                  const float* __restrict__ kg) {
  __shared__ __align__(16) bf16 As[2][4096];  // [buf][128 rows][32 cols] swizzled
  __shared__ __align__(16) bf16 Bs[2][8192];  // [buf][256 rows][32 cols] swizzled

  const int tid = threadIdx.x;
  const int lane = tid & 63;
  const int w = tid >> 6;
  const int quad = lane >> 4;
  const int l16 = lane & 15;
  const int wr = w >> 2;
  const int wc = w & 3;

  // bijective XCD swizzle (nwg = 768, %8 == 0)
  const int gx = gridDim.x;  // 12
  const int bid = blockIdx.y * gx + blockIdx.x;
  const int cpx = (gx * gridDim.y) >> 3;
  const int sw = (bid & 7) * cpx + (bid >> 3);
  const int n0 = (sw % gx) * 256;
  const int m0 = (sw / gx) * 128;

  const int srA = tid >> 2;                         // 0..127
  const int scS = ((tid & 3) ^ ((tid >> 3) & 3)) * 8;
  const bf16* aS = A + (long)(m0 + srA) * K + scS;
  const bf16* bS0 = Bt + (long)(n0 + srA) * K + scS;
  const bf16* bS1 = bS0 + (long)128 * K;

#define STAGE(tb, kt1)                                                   \
  {                                                                      \
    const long kc = (long)(kt1)*32;                                      \
    gl_lds16(aS + kc, &As[tb][w * 512]);                                 \
    gl_lds16(bS0 + kc, &Bs[tb][w * 512]);                                \
    gl_lds16(bS1 + kc, &Bs[tb][4096 + w * 512]);                         \
  }

  const int cphys = (quad ^ ((l16 >> 1) & 3)) * 8;
  const int aoff = (wr * 64 + l16) * 32 + cphys;
  const int boff = (wc * 64 + l16) * 32 + cphys;

  f32x4 acc[4][4];
#pragma unroll
  for (int i = 0; i < 4; i++)
#pragma unroll
    for (int j = 0; j < 4; j++) acc[i][j] = f32x4{0.f, 0.f, 0.f, 0.f};

  const int NK = K >> 5;  // 32
  STAGE(0, 0);

  for (int kt = 0; kt < NK; ++kt) {
    const int pb = kt & 1;
    const int tb = pb ^ 1;
    const bool pf = (kt + 1 < NK);
    if (pf) {
      STAGE(tb, kt + 1);
      asm volatile("s_waitcnt vmcnt(3)" ::: "memory");
    } else {
      asm volatile("s_waitcnt vmcnt(0)" ::: "memory");
    }
    BAR();
    bf16x8 afr[4], bfr[4];
#pragma unroll
    for (int n = 0; n < 4; n++) bfr[n] = *(const bf16x8*)&Bs[pb][boff + n * 512];
#pragma unroll
    for (int m = 0; m < 4; m++) afr[m] = *(const bf16x8*)&As[pb][aoff + m * 512];
    __builtin_amdgcn_s_setprio(1);
#pragma unroll
    for (int m = 0; m < 4; m++)
#pragma unroll
      for (int n = 0; n < 4; n++)
        acc[m][n] = __builtin_amdgcn_mfma_f32_16x16x32_bf16(afr[m], bfr[n], acc[m][n], 0, 0, 0);
    __builtin_amdgcn_s_setprio(0);
    BAR();
  }

  // ---------------- epilogue (m89/m91 C layout)
  const int which = n0 >> 10;  // 0=q, 1=k, 2=v
  if (which == 2) {
    const int T0 = (((m0 & 1023) + wr * 64) >> 2) + quad;
    const int bh = (m0 >> 10) * 16 + (((n0 + wc * 64) & 1023) >> 6);
#pragma unroll
    for (int m = 0; m < 4; m++) {
#pragma unroll
      for (int n = 0; n < 4; n++) {
        int ng = n0 + wc * 64 + n * 16 + l16;
        int dc = n * 16 + l16;
        float bj = bias[ng];
        bf16x4 pv;
#pragma unroll
        for (int r = 0; r < 4; r++) pv[r] = (bf16)(acc[m][n][r] + bj);
        *(bf16x4*)(v4 + ((long)bh * 16384 + (long)(T0 + m * 4) * 64 + dc) * 4) = pv;
      }
    }
    return;
  }

  const float* gg = which ? kg : qg;
  bf16* dst = which ? kb : qb;
  const float fold = which ? 1.0f : 8.0f;
  const int h = ((n0 + wc * 64) & 1023) >> 6;
  const int bh = (m0 >> 10) * 16 + h;
  float bj[4], gain[4];
#pragma unroll
  for (int j = 0; j < 4; j++) {
    bj[j] = bias[n0 + wc * 64 + j * 16 + l16];
    gain[j] = gg[j * 16 + l16];
  }
  const float f = exp2f((float)l16 * (-13.287712379549449f / 16.0f));  // 10000^(-l16/16)

#pragma unroll
  for (int m = 0; m < 4; m++) {
#pragma unroll
    for (int r = 0; r < 4; r++) {
      int ntok = (m0 & 1023) + wr * 64 + m * 16 + quad * 4 + r;
      float v0 = acc[m][0][r] + bj[0];
      float v1 = acc[m][1][r] + bj[1];
      float v2 = acc[m][2][r] + bj[2];
      float v3 = acc[m][3][r] + bj[3];
      float ss = v0 * v0 + v1 * v1 + v2 * v2 + v3 * v3;
#pragma unroll
      for (int mk = 1; mk <= 8; mk <<= 1) ss += __shfl_xor(ss, mk, 64);
      float rms = rsqrtf(ss * (1.0f / 64.0f) + 1e-6f);
      v0 *= rms * gain[0]; v1 *= rms * gain[1]; v2 *= rms * gain[2]; v3 *= rms * gain[3];
      float sh, ch_, swv, cw;
      __sincosf((float)(ntok >> 5) * f, &sh, &ch_);
      __sincosf((float)(ntok & 31) * f, &swv, &cw);
      float w0 = v0 * ch_ - v2 * sh;
      float w1 = v1 * cw - v3 * swv;
      float w2 = v2 * ch_ + v0 * sh;
      float w3 = v3 * cw + v1 * swv;
      float nn = w0 * w0 + w1 * w1 + w2 * w2 + w3 * w3;
#pragma unroll
      for (int mk = 1; mk <= 8; mk <<= 1) nn += __shfl_xor(nn, mk, 64);
      float inv = rsqrtf(nn) * fold;
      long base = ((long)bh * 1024 + ntok) * 64 + l16;
      dst[base] = (bf16)(w0 * inv);
      dst[base + 16] = (bf16)(w1 * inv);
      dst[base + 32] = (bf16)(w2 * inv);
      dst[base + 48] = (bf16)(w3 * inv);
    }
  }
}

// ---------------------------------------------------------------- out-proj GEMM 128^2
// r5: r4 recipe applied — dbuf LDS (32KB), raw s_barrier, counted vmcnt(4), XOR
// swizzle via pre-swizzled source (kills r0's 6.3M bank conflicts), setprio.
// grid (8,64) = 512 blocks = 2/CU; A = attention-out in (b,h,tok,d) layout (qb).
__global__ __launch_bounds__(256, 4) void gemm_bt1(const bf16* __restrict__ A,
                                                   const bf16* __restrict__ Bt,
                                                   const float* __restrict__ bias,
                                                   int N, int K,
                                                   float* __restrict__ out) {
  __shared__ __align__(16) bf16 As[2][4096];  // [buf][128][32] swizzled
  __shared__ __align__(16) bf16 Bs[2][4096];

  const int tid = threadIdx.x;
  const int lane = tid & 63;
  const int w = tid >> 6;
  const int wm = (w & 1) * 64;
  const int wn = (w >> 1) * 64;
  const int quad = lane >> 4;
  const int l16 = lane & 15;

  const int m0 = blockIdx.y * 128;
  const int n0 = blockIdx.x * 128;

  // staging slots: s = l*256+tid (512 slots); row = s>>2, phys chunk = s&3 holds
  // logical chunk (s&3)^((s>>3)&3) -> pre-swizzled source, linear LDS dest
  int srow[2], scof[2];
#pragma unroll
  for (int l = 0; l < 2; l++) {
    int s = l * 256 + tid;
    srow[l] = s >> 2;
    scof[l] = ((s & 3) ^ ((s >> 3) & 3)) * 8;
  }

  auto stage = [&](int tb, int k0) {
    int hh = k0 >> 6;
#pragma unroll
    for (int l = 0; l < 2; l++) {
      int m1 = m0 + srow[l];
      int dc = (k0 & 63) + scof[l];
      const bf16* ga = A + ((long)((m1 >> 10) * 16 + hh) * 1024 + (m1 & 1023)) * 64 + dc;
      gl_lds16(ga, &As[tb][l * 2048 + w * 512]);
      gl_lds16(Bt + (long)(n0 + srow[l]) * K + k0 + scof[l], &Bs[tb][l * 2048 + w * 512]);
    }
  };

  const int cphys = (quad ^ ((l16 >> 1) & 3)) * 8;

  f32x4 acc[4][4];
#pragma unroll
  for (int i = 0; i < 4; i++)
#pragma unroll
    for (int j = 0; j < 4; j++) acc[i][j] = f32x4{0.f, 0.f, 0.f, 0.f};

  const int NK = K >> 5;  // 32
  stage(0, 0);

  for (int kt = 0; kt < NK; ++kt) {
    const int pb = kt & 1;
    const int tb = pb ^ 1;
    const bool pf = (kt + 1 < NK);
    if (pf) {
      stage(tb, (kt + 1) << 5);
      asm volatile("s_waitcnt vmcnt(4)" ::: "memory");
    } else {
      asm volatile("s_waitcnt vmcnt(0)" ::: "memory");
    }
    BAR();
    bf16x8 af[4], bfr[4];
#pragma unroll
    for (int i = 0; i < 4; i++) {
      af[i] = *(const bf16x8*)&As[pb][(wm + i * 16 + l16) * 32 + cphys];
      bfr[i] = *(const bf16x8*)&Bs[pb][(wn + i * 16 + l16) * 32 + cphys];
    }
    __builtin_amdgcn_s_setprio(1);
#pragma unroll
    for (int i = 0; i < 4; i++)
#pragma unroll
      for (int j = 0; j < 4; j++)
        acc[i][j] = __builtin_amdgcn_mfma_f32_16x16x32_bf16(af[i], bfr[j], acc[i][j], 0, 0, 0);
    __builtin_amdgcn_s_setprio(0);
    BAR();
  }

#pragma unroll
  for (int i = 0; i < 4; i++)
#pragma unroll
    for (int j = 0; j < 4; j++)
#pragma unroll
      for (int r = 0; r < 4; r++) {
        int mg = m0 + wm + i * 16 + quad * 4 + r;
        int ng = n0 + wn + j * 16 + l16;
        out[(long)mg * N + ng] = acc[i][j][r] + bias[ng];
      }
}

// ---------------------------------------------------------------- flash attention (fixed-max softmax)
// r5: P software-pipelined through LDS across groups. Same-wave DS ops complete
// in-order, so no explicit drain between store-P and read-P; reads for group g are
// issued right after its stores, and consumed one group later — read latency hides
// under QK[g+1]'s 8 MFMA. Compiler inserts the counted register-dep waits.
// K/V staging double-buffered with raw barriers (r3/r4 structure).
__global__ __launch_bounds__(256, 2) void attn_k(bf16* __restrict__ qb,
                                                 const bf16* __restrict__ kb,
                                                 const bf16* __restrict__ v4) {
  __shared__ __align__(16) bf16 Ks[2][64][72];     // keys x d (padded, dbuf)
  __shared__ __align__(16) bf16 Vl[2][4096];       // linear v4 tile (dbuf)
  __shared__ __align__(16) bf16 Ps[4][2][16][72];  // per-wave P, 2 pipeline slots

  const int tid = threadIdx.x;
  const int lane = tid & 63;
  const int w = tid >> 6;
  const int quad = lane >> 4;
  const int l16 = lane & 15;

  const int bh = blockIdx.y;
  const int q0 = blockIdx.x * 256 + w * 64;

  // Q fragments for 4 query groups (q already holds cos-sim scale 8)
  bf16x8 aq[4][2];
  long qrow[4];
#pragma unroll
  for (int g = 0; g < 4; g++) {
    qrow[g] = ((long)bh * 1024 + q0 + g * 16 + l16) * 64;
    aq[g][0] = *(const bf16x8*)(qb + qrow[g] + quad * 8);
    aq[g][1] = *(const bf16x8*)(qb + qrow[g] + 32 + quad * 8);
  }

  f32x4 o[4][4];
#pragma unroll
  for (int g = 0; g < 4; g++)
#pragma unroll
    for (int i = 0; i < 4; i++) o[g][i] = f32x4{0.f, 0.f, 0.f, 0.f};
  float ls[4] = {0.f, 0.f, 0.f, 0.f};

  const int sr = tid >> 3, sc = (tid & 7) * 8;  // K staging: 32 rows x 64 cols per load
  const bf16* kbase = kb + (long)bh * 65536;
  const bf16* vbase = v4 + (long)bh * 65536;

  // prologue: stage tile 0 into buffer 0
  bf16x8 kr0 = *(const bf16x8*)(kbase + (long)sr * 64 + sc);
  bf16x8 kr1 = *(const bf16x8*)(kbase + (long)(sr + 32) * 64 + sc);
  gl_lds16(vbase + (w * 2) * 512 + lane * 8, &Vl[0][(w * 2) * 512]);
  gl_lds16(vbase + (w * 2 + 1) * 512 + lane * 8, &Vl[0][(w * 2 + 1) * 512]);
  asm volatile("s_waitcnt vmcnt(0)" ::: "memory");
  *(bf16x8*)&Ks[0][sr][sc] = kr0;
  *(bf16x8*)&Ks[0][sr + 32][sc] = kr1;
  asm volatile("s_waitcnt lgkmcnt(0)" ::: "memory");
  BAR();

  for (int kt = 0; kt < 1024; kt += 64) {
    const int cur = (kt >> 6) & 1;
    const bool pf = (kt + 64 < 1024);
    // issue next tile's staging loads (K -> regs, V -> alternate LDS buffer)
    if (pf) {
      kr0 = *(const bf16x8*)(kbase + (long)(kt + 64 + sr) * 64 + sc);
      kr1 = *(const bf16x8*)(kbase + (long)(kt + 64 + sr + 32) * 64 + sc);
      gl_lds16(vbase + (long)(kt + 64) * 64 + (w * 2) * 512 + lane * 8,
               &Vl[cur ^ 1][(w * 2) * 512]);
      gl_lds16(vbase + (long)(kt + 64) * 64 + (w * 2 + 1) * 512 + lane * 8,
               &Vl[cur ^ 1][(w * 2 + 1) * 512]);
    }

    // hoist K-frags and V-frags for this tile
    bf16x8 kf[4][2], vf[4][2];
#pragma unroll
    for (int i = 0; i < 4; i++) {
      kf[i][0] = *(const bf16x8*)&Ks[cur][i * 16 + l16][quad * 8];
      kf[i][1] = *(const bf16x8*)&Ks[cur][i * 16 + l16][32 + quad * 8];
      int D4 = (i * 16 + l16) * 4;
      bf16x4 a0 = *(const bf16x4*)&Vl[cur][quad * 512 + D4];
      bf16x4 a1 = *(const bf16x4*)&Vl[cur][quad * 512 + D4 + 256];
      bf16x4 a2 = *(const bf16x4*)&Vl[cur][quad * 512 + D4 + 2048];
      bf16x4 a3 = *(const bf16x4*)&Vl[cur][quad * 512 + D4 + 2048 + 256];
      vf[i][0] = __builtin_shufflevector(a0, a1, 0, 1, 2, 3, 4, 5, 6, 7);
      vf[i][1] = __builtin_shufflevector(a2, a3, 0, 1, 2, 3, 4, 5, 6, 7);
    }

    bf16x8 bp[2][2];
#pragma unroll
    for (int g = 0; g < 4; g++) {
      const int sl = g & 1;
      // St = K_tile · Qg^T ; p = exp(s-8); per-lane l partial (column q=l16)
#pragma unroll
      for (int i = 0; i < 4; i++) {
        f32x4 st = f32x4{0.f, 0.f, 0.f, 0.f};
        st = __builtin_amdgcn_mfma_f32_16x16x32_bf16(kf[i][0], aq[g][0], st, 0, 0, 0);
        st = __builtin_amdgcn_mfma_f32_16x16x32_bf16(kf[i][1], aq[g][1], st, 0, 0, 0);
        bf16x4 pk;
#pragma unroll
        for (int r = 0; r < 4; r++) {
          float p = __expf(st[r] - 8.0f);
          ls[g] += p;
          pk[r] = (bf16)p;
        }
        *(bf16x4*)&Ps[w][sl][l16][i * 16 + quad * 4] = pk;
      }
      // issue this group's P reads immediately (in-order DS: RAW safe, no drain);
      // they complete under the NEXT group's QK MFMAs.
      bp[sl][0] = *(const bf16x8*)&Ps[w][sl][l16][quad * 8];
      bp[sl][1] = *(const bf16x8*)&Ps[w][sl][l16][32 + quad * 8];
      if (g > 0) {
        const int pg = (g - 1) & 1;
#pragma unroll
        for (int i = 0; i < 4; i++) {
          o[g - 1][i] = __builtin_amdgcn_mfma_f32_16x16x32_bf16(vf[i][0], bp[pg][0], o[g - 1][i], 0, 0, 0);
          o[g - 1][i] = __builtin_amdgcn_mfma_f32_16x16x32_bf16(vf[i][1], bp[pg][1], o[g - 1][i], 0, 0, 0);
        }
      }
    }
    // pipeline drain: PV for group 3
#pragma unroll
    for (int i = 0; i < 4; i++) {
      o[3][i] = __builtin_amdgcn_mfma_f32_16x16x32_bf16(vf[i][0], bp[1][0], o[3][i], 0, 0, 0);
      o[3][i] = __builtin_amdgcn_mfma_f32_16x16x32_bf16(vf[i][1], bp[1][1], o[3][i], 0, 0, 0);
    }

    // commit next tile: wait K regs + V gl_lds (covered by the g-loop), write K to LDS
    if (pf) {
      asm volatile("s_waitcnt vmcnt(0)" ::: "memory");
      *(bf16x8*)&Ks[cur ^ 1][sr][sc] = kr0;
      *(bf16x8*)&Ks[cur ^ 1][sr + 32][sc] = kr1;
    }
    asm volatile("s_waitcnt lgkmcnt(0)" ::: "memory");
    BAR();
  }

#pragma unroll
  for (int g = 0; g < 4; g++) {
    float l = ls[g];
    l += __shfl_xor(l, 16, 64);
    l += __shfl_xor(l, 32, 64);
    float inv = 1.0f / l;
#pragma unroll
    for (int i = 0; i < 4; i++) {
      bf16x4 ov;
#pragma unroll
      for (int r = 0; r < 4; r++) ov[r] = (bf16)(o[g][i][r] * inv);
      *(bf16x4*)(qb + qrow[g] + i * 16 + quad * 4) = ov;
    }
  }
}

// ---------------------------------------------------------------- launcher
extern "C" void kernel_launch(void* const* d_in, const int* in_sizes, int n_in,
                              void* d_out, int out_size, void* d_ws, size_t ws_size,
                              hipStream_t stream) {
  (void)in_sizes; (void)n_in; (void)out_size; (void)ws_size;
  const float* x     = (const float*)d_in[0];
  const float* w_qkv = (const float*)d_in[1];
  const float* b_qkv = (const float*)d_in[2];
  const float* q_g   = (const float*)d_in[3];
  const float* k_g   = (const float*)d_in[4];
  const float* w_out = (const float*)d_in[5];
  const float* b_out = (const float*)d_in[6];
  float* out = (float*)d_out;

  char* ws = (char*)d_ws;
  bf16* wqkvT = (bf16*)ws; ws += (long)3072 * 1024 * 2;      // 6 MB
  bf16* woT   = (bf16*)ws; ws += (long)1024 * 1024 * 2;      // 2 MB
  bf16* xb    = (bf16*)ws; ws += (long)8192 * 1024 * 2;      // 16 MB
  bf16* qb    = (bf16*)ws; ws += (long)128 * 1024 * 64 * 2;  // 16 MB (q, then attention O)
  bf16* kb    = (bf16*)ws; ws += (long)128 * 1024 * 64 * 2;  // 16 MB
  bf16* v4    = (bf16*)ws; ws += (long)128 * 64 * 1024 * 2;  // 16 MB   (total 72 MB)

  prep_k<<<8192, 256, 0, stream>>>(x, xb, w_qkv, wqkvT, w_out, woT);
  gemm256<<<dim3(3072 / 256, 8192 / 128), 512, 0, stream>>>(xb, wqkvT, b_qkv, 1024,
                                                            qb, kb, v4, q_g, k_g);
  attn_k<<<dim3(4, 128), 256, 0, stream>>>(qb, kb, v4);
  gemm_bt1<<<dim3(1024 / 128, 8192 / 128), 256, 0, stream>>>(qb, woT, b_out,
                                                             1024, 1024, out);
}

// Round 6
// 242.674 us; speedup vs baseline: 1.0981x; 1.0136x over previous
//
#include <hip/hip_runtime.h>
#include <hip/hip_bf16.h>
#include <cstdint>

typedef __bf16 bf16;
typedef __bf16 bf16x8 __attribute__((ext_vector_type(8)));
typedef __bf16 bf16x4 __attribute__((ext_vector_type(4)));
typedef float f32x4 __attribute__((ext_vector_type(4)));

__device__ inline bf16x8 cvt8(const float* __restrict__ p) {
  float4 a = *(const float4*)p;
  float4 b = *(const float4*)(p + 4);
  bf16x8 r;
  r[0] = (bf16)a.x; r[1] = (bf16)a.y; r[2] = (bf16)a.z; r[3] = (bf16)a.w;
  r[4] = (bf16)b.x; r[5] = (bf16)b.y; r[6] = (bf16)b.z; r[7] = (bf16)b.w;
  return r;
}

// async global->LDS, 16B per lane; LDS dest = wave-uniform base + lane*16 (m97/m104)
__device__ inline void gl_lds16(const bf16* g, bf16* l) {
  auto gp = reinterpret_cast<const __attribute__((address_space(1))) uint32_t*>(
      reinterpret_cast<uintptr_t>(g));
  auto lp = reinterpret_cast<__attribute__((address_space(3))) uint32_t*>(
      reinterpret_cast<uintptr_t>(l));
  __builtin_amdgcn_global_load_lds(gp, lp, 16, 0, 0);
}

#define BAR() asm volatile("s_barrier" ::: "memory")

// ---------------------------------------------------------------- fused prep:
// blocks [0,4096): fp32->bf16 cast of x
// blocks [4096,7168): transpose+cast w_qkv (1024x3072 -> 3072x1024)
// blocks [7168,8192): transpose+cast w_out (1024x1024 -> 1024x1024)
__global__ __launch_bounds__(256) void prep_k(const float* __restrict__ x,
                                              bf16* __restrict__ xb,
                                              const float* __restrict__ wqkv,
                                              bf16* __restrict__ wqkvT,
                                              const float* __restrict__ wo,
                                              bf16* __restrict__ woT) {
  __shared__ bf16 T[32][33];
  const int bid = blockIdx.x;
  if (bid < 4096) {
    long i = ((long)bid * 256 + threadIdx.x) * 8;
    *(bf16x8*)(xb + i) = cvt8(x + i);
    return;
  }
  const float* in;
  bf16* out;
  int R, C, bx, by;
  if (bid < 7168) {
    int t = bid - 4096;
    in = wqkv; out = wqkvT; R = 1024; C = 3072;
    bx = t % 96; by = t / 96;
  } else {
    int t = bid - 7168;
    in = wo; out = woT; R = 1024; C = 1024;
    bx = t % 32; by = t / 32;
  }
  int tc = bx * 32, tr = by * 32;
  int c = threadIdx.x & 31, r8 = threadIdx.x >> 5;
#pragma unroll
  for (int i = 0; i < 4; i++) {
    int r = r8 + i * 8;
    T[r][c] = (bf16)in[(long)(tr + r) * C + tc + c];
  }
  __syncthreads();
#pragma unroll
  for (int i = 0; i < 4; i++) {
    int r = r8 + i * 8;
    out[(long)(tc + r) * R + tr + c] = T[c][r];
  }
}

// ---------------------------------------------------------------- 128x256 QKV GEMM, 3 blocks/CU
// r6: rotated software pipeline — per K-step: MFMA(frags kt in regs) -> vmcnt(0)
// [STAGE(kt+1), issued a full iteration earlier, has HBM latency fully covered] ->
// ONE raw s_barrier -> ds_read frags(kt+1) [latency hides under next MFMA via
// compiler lgkmcnt] -> STAGE(kt+2) into the buffer MFMA(kt) just freed.
// Fixes r5's lockstep serialization (read-phase || MFMA-phase were serial: MfmaUtil
// 28% = MFMA / (MFMA+LDS+VALU) sum). Geometry/swizzle/occupancy = r4 proven.
__global__ __launch_bounds__(512, 4) void gemm256(const bf16* __restrict__ A,
                                                  const bf16* __restrict__ Bt,
                                                  const float* __restrict__ bias,
                                                  int K,
                                                  bf16* __restrict__ qb,
                                                  bf16* __restrict__ kb,
                                                  bf16* __restrict__ v4,
                                                  const float* __restrict__ qg,
                                                  const float* __restrict__ kg) {
  __shared__ __align__(16) bf16 As[2][4096];  // [buf][128 rows][32 cols] swizzled
  __shared__ __align__(16) bf16 Bs[2][8192];  // [buf][256 rows][32 cols] swizzled

  const int tid = threadIdx.x;
  const int lane = tid & 63;
  const int w = tid >> 6;
  const int quad = lane >> 4;
  const int l16 = lane & 15;
  const int wr = w >> 2;
  const int wc = w & 3;

  // bijective XCD swizzle (nwg = 768, %8 == 0)
  const int gx = gridDim.x;  // 12
  const int bid = blockIdx.y * gx + blockIdx.x;
  const int cpx = (gx * gridDim.y) >> 3;
  const int sw = (bid & 7) * cpx + (bid >> 3);
  const int n0 = (sw % gx) * 256;
  const int m0 = (sw / gx) * 128;

  const int srA = tid >> 2;                         // 0..127
  const int scS = ((tid & 3) ^ ((tid >> 3) & 3)) * 8;
  const bf16* aS = A + (long)(m0 + srA) * K + scS;
  const bf16* bS0 = Bt + (long)(n0 + srA) * K + scS;
  const bf16* bS1 = bS0 + (long)128 * K;

#define STAGE(tb, kt1)                                                   \
  {                                                                      \
    const long kc = (long)(kt1)*32;                                      \
    gl_lds16(aS + kc, &As[tb][w * 512]);                                 \
    gl_lds16(bS0 + kc, &Bs[tb][w * 512]);                                \
    gl_lds16(bS1 + kc, &Bs[tb][4096 + w * 512]);                         \
  }

  const int cphys = (quad ^ ((l16 >> 1) & 3)) * 8;
  const int aoff = (wr * 64 + l16) * 32 + cphys;
  const int boff = (wc * 64 + l16) * 32 + cphys;

#define LOADFRAGS(pb)                                                          \
  {                                                                            \
    _Pragma("unroll") for (int n = 0; n < 4; n++) bfr[n] =                     \
        *(const bf16x8*)&Bs[pb][boff + n * 512];                               \
    _Pragma("unroll") for (int m = 0; m < 4; m++) afr[m] =                     \
        *(const bf16x8*)&As[pb][aoff + m * 512];                               \
  }

  f32x4 acc[4][4];
#pragma unroll
  for (int i = 0; i < 4; i++)
#pragma unroll
    for (int j = 0; j < 4; j++) acc[i][j] = f32x4{0.f, 0.f, 0.f, 0.f};

  const int NK = K >> 5;  // 32
  bf16x8 afr[4], bfr[4];

  // prologue: stage tile0 -> b0, read its frags, stage tile1 -> b1
  STAGE(0, 0);
  asm volatile("s_waitcnt vmcnt(0)" ::: "memory");
  BAR();
  LOADFRAGS(0);
  STAGE(1, 1);

  for (int kt = 0; kt < NK; ++kt) {
    __builtin_amdgcn_s_setprio(1);
#pragma unroll
    for (int m = 0; m < 4; m++)
#pragma unroll
      for (int n = 0; n < 4; n++)
        acc[m][n] = __builtin_amdgcn_mfma_f32_16x16x32_bf16(afr[m], bfr[n], acc[m][n], 0, 0, 0);
    __builtin_amdgcn_s_setprio(0);
    if (kt + 1 < NK) {
      asm volatile("s_waitcnt vmcnt(0)" ::: "memory");  // STAGE(kt+1) landed (1 iter of cover)
      BAR();  // every wave past MFMA(kt) => its reads of buf[kt&1] are complete
      LOADFRAGS((kt + 1) & 1);
      if (kt + 2 < NK) STAGE(kt & 1, kt + 2);  // refill the buffer MFMA(kt) freed
    }
  }

  // ---------------- epilogue (m89/m91 C layout)
  const int which = n0 >> 10;  // 0=q, 1=k, 2=v
  if (which == 2) {
    const int T0 = (((m0 & 1023) + wr * 64) >> 2) + quad;
    const int bh = (m0 >> 10) * 16 + (((n0 + wc * 64) & 1023) >> 6);
#pragma unroll
    for (int m = 0; m < 4; m++) {
#pragma unroll
      for (int n = 0; n < 4; n++) {
        int ng = n0 + wc * 64 + n * 16 + l16;
        int dc = n * 16 + l16;
        float bj = bias[ng];
        bf16x4 pv;
#pragma unroll
        for (int r = 0; r < 4; r++) pv[r] = (bf16)(acc[m][n][r] + bj);
        *(bf16x4*)(v4 + ((long)bh * 16384 + (long)(T0 + m * 4) * 64 + dc) * 4) = pv;
      }
    }
    return;
  }

  const float* gg = which ? kg : qg;
  bf16* dst = which ? kb : qb;
  const float fold = which ? 1.0f : 8.0f;
  const int h = ((n0 + wc * 64) & 1023) >> 6;
  const int bh = (m0 >> 10) * 16 + h;
  float bj[4], gain[4];
#pragma unroll
  for (int j = 0; j < 4; j++) {
    bj[j] = bias[n0 + wc * 64 + j * 16 + l16];
    gain[j] = gg[j * 16 + l16];
  }
  const float f = exp2f((float)l16 * (-13.287712379549449f / 16.0f));  // 10000^(-l16/16)

#pragma unroll
  for (int m = 0; m < 4; m++) {
#pragma unroll
    for (int r = 0; r < 4; r++) {
      int ntok = (m0 & 1023) + wr * 64 + m * 16 + quad * 4 + r;
      float v0 = acc[m][0][r] + bj[0];
      float v1 = acc[m][1][r] + bj[1];
      float v2 = acc[m][2][r] + bj[2];
      float v3 = acc[m][3][r] + bj[3];
      float ss = v0 * v0 + v1 * v1 + v2 * v2 + v3 * v3;
#pragma unroll
      for (int mk = 1; mk <= 8; mk <<= 1) ss += __shfl_xor(ss, mk, 64);
      float rms = rsqrtf(ss * (1.0f / 64.0f) + 1e-6f);
      v0 *= rms * gain[0]; v1 *= rms * gain[1]; v2 *= rms * gain[2]; v3 *= rms * gain[3];
      float sh, ch_, swv, cw;
      __sincosf((float)(ntok >> 5) * f, &sh, &ch_);
      __sincosf((float)(ntok & 31) * f, &swv, &cw);
      float w0 = v0 * ch_ - v2 * sh;
      float w1 = v1 * cw - v3 * swv;
      float w2 = v2 * ch_ + v0 * sh;
      float w3 = v3 * cw + v1 * swv;
      float nn = w0 * w0 + w1 * w1 + w2 * w2 + w3 * w3;
#pragma unroll
      for (int mk = 1; mk <= 8; mk <<= 1) nn += __shfl_xor(nn, mk, 64);
      float inv = rsqrtf(nn) * fold;
      long base = ((long)bh * 1024 + ntok) * 64 + l16;
      dst[base] = (bf16)(w0 * inv);
      dst[base + 16] = (bf16)(w1 * inv);
      dst[base + 32] = (bf16)(w2 * inv);
      dst[base + 48] = (bf16)(w3 * inv);
    }
  }
}

// ---------------------------------------------------------------- out-proj GEMM 128^2
// r6: same rotated pipeline as gemm256 (MFMA -> vmcnt(0) -> BAR -> reads -> stage).
__global__ __launch_bounds__(256, 4) void gemm_bt1(const bf16* __restrict__ A,
                                                   const bf16* __restrict__ Bt,
                                                   const float* __restrict__ bias,
                                                   int N, int K,
                                                   float* __restrict__ out) {
  __shared__ __align__(16) bf16 As[2][4096];  // [buf][128][32] swizzled
  __shared__ __align__(16) bf16 Bs[2][4096];

  const int tid = threadIdx.x;
  const int lane = tid & 63;
  const int w = tid >> 6;
  const int wm = (w & 1) * 64;
  const int wn = (w >> 1) * 64;
  const int quad = lane >> 4;
  const int l16 = lane & 15;

  const int m0 = blockIdx.y * 128;
  const int n0 = blockIdx.x * 128;

  int srow[2], scof[2];
#pragma unroll
  for (int l = 0; l < 2; l++) {
    int s = l * 256 + tid;
    srow[l] = s >> 2;
    scof[l] = ((s & 3) ^ ((s >> 3) & 3)) * 8;
  }

  auto stage = [&](int tb, int k0) {
    int hh = k0 >> 6;
#pragma unroll
    for (int l = 0; l < 2; l++) {
      int m1 = m0 + srow[l];
      int dc = (k0 & 63) + scof[l];
      const bf16* ga = A + ((long)((m1 >> 10) * 16 + hh) * 1024 + (m1 & 1023)) * 64 + dc;
      gl_lds16(ga, &As[tb][l * 2048 + w * 512]);
      gl_lds16(Bt + (long)(n0 + srow[l]) * K + k0 + scof[l], &Bs[tb][l * 2048 + w * 512]);
    }
  };

  const int cphys = (quad ^ ((l16 >> 1) & 3)) * 8;

  f32x4 acc[4][4];
#pragma unroll
  for (int i = 0; i < 4; i++)
#pragma unroll
    for (int j = 0; j < 4; j++) acc[i][j] = f32x4{0.f, 0.f, 0.f, 0.f};

  const int NK = K >> 5;  // 32
  bf16x8 af[4], bfr[4];

#define LOADFRAGS1(pb)                                                         \
  {                                                                            \
    _Pragma("unroll") for (int i = 0; i < 4; i++) {                            \
      af[i] = *(const bf16x8*)&As[pb][(wm + i * 16 + l16) * 32 + cphys];       \
      bfr[i] = *(const bf16x8*)&Bs[pb][(wn + i * 16 + l16) * 32 + cphys];      \
    }                                                                          \
  }

  stage(0, 0);
  asm volatile("s_waitcnt vmcnt(0)" ::: "memory");
  BAR();
  LOADFRAGS1(0);
  stage(1, 32);

  for (int kt = 0; kt < NK; ++kt) {
    __builtin_amdgcn_s_setprio(1);
#pragma unroll
    for (int i = 0; i < 4; i++)
#pragma unroll
      for (int j = 0; j < 4; j++)
        acc[i][j] = __builtin_amdgcn_mfma_f32_16x16x32_bf16(af[i], bfr[j], acc[i][j], 0, 0, 0);
    __builtin_amdgcn_s_setprio(0);
    if (kt + 1 < NK) {
      asm volatile("s_waitcnt vmcnt(0)" ::: "memory");
      BAR();
      LOADFRAGS1((kt + 1) & 1);
      if (kt + 2 < NK) stage(kt & 1, (kt + 2) << 5);
    }
  }

#pragma unroll
  for (int i = 0; i < 4; i++)
#pragma unroll
    for (int j = 0; j < 4; j++)
#pragma unroll
      for (int r = 0; r < 4; r++) {
        int mg = m0 + wm + i * 16 + quad * 4 + r;
        int ng = n0 + wn + j * 16 + l16;
        out[(long)mg * N + ng] = acc[i][j][r] + bias[ng];
      }
}

// ---------------------------------------------------------------- flash attention (fixed-max softmax)
// r5 structure (unchanged this round to isolate the GEMM A/B): P software-pipelined
// through LDS across groups; K/V staging double-buffered with raw barriers.
__global__ __launch_bounds__(256, 2) void attn_k(bf16* __restrict__ qb,
                                                 const bf16* __restrict__ kb,
                                                 const bf16* __restrict__ v4) {
  __shared__ __align__(16) bf16 Ks[2][64][72];     // keys x d (padded, dbuf)
  __shared__ __align__(16) bf16 Vl[2][4096];       // linear v4 tile (dbuf)
  __shared__ __align__(16) bf16 Ps[4][2][16][72];  // per-wave P, 2 pipeline slots

  const int tid = threadIdx.x;
  const int lane = tid & 63;
  const int w = tid >> 6;
  const int quad = lane >> 4;
  const int l16 = lane & 15;

  const int bh = blockIdx.y;
  const int q0 = blockIdx.x * 256 + w * 64;

  bf16x8 aq[4][2];
  long qrow[4];
#pragma unroll
  for (int g = 0; g < 4; g++) {
    qrow[g] = ((long)bh * 1024 + q0 + g * 16 + l16) * 64;
    aq[g][0] = *(const bf16x8*)(qb + qrow[g] + quad * 8);
    aq[g][1] = *(const bf16x8*)(qb + qrow[g] + 32 + quad * 8);
  }

  f32x4 o[4][4];
#pragma unroll
  for (int g = 0; g < 4; g++)
#pragma unroll
    for (int i = 0; i < 4; i++) o[g][i] = f32x4{0.f, 0.f, 0.f, 0.f};
  float ls[4] = {0.f, 0.f, 0.f, 0.f};

  const int sr = tid >> 3, sc = (tid & 7) * 8;
  const bf16* kbase = kb + (long)bh * 65536;
  const bf16* vbase = v4 + (long)bh * 65536;

  bf16x8 kr0 = *(const bf16x8*)(kbase + (long)sr * 64 + sc);
  bf16x8 kr1 = *(const bf16x8*)(kbase + (long)(sr + 32) * 64 + sc);
  gl_lds16(vbase + (w * 2) * 512 + lane * 8, &Vl[0][(w * 2) * 512]);
  gl_lds16(vbase + (w * 2 + 1) * 512 + lane * 8, &Vl[0][(w * 2 + 1) * 512]);
  asm volatile("s_waitcnt vmcnt(0)" ::: "memory");
  *(bf16x8*)&Ks[0][sr][sc] = kr0;
  *(bf16x8*)&Ks[0][sr + 32][sc] = kr1;
  asm volatile("s_waitcnt lgkmcnt(0)" ::: "memory");
  BAR();

  for (int kt = 0; kt < 1024; kt += 64) {
    const int cur = (kt >> 6) & 1;
    const bool pf = (kt + 64 < 1024);
    if (pf) {
      kr0 = *(const bf16x8*)(kbase + (long)(kt + 64 + sr) * 64 + sc);
      kr1 = *(const bf16x8*)(kbase + (long)(kt + 64 + sr + 32) * 64 + sc);
      gl_lds16(vbase + (long)(kt + 64) * 64 + (w * 2) * 512 + lane * 8,
               &Vl[cur ^ 1][(w * 2) * 512]);
      gl_lds16(vbase + (long)(kt + 64) * 64 + (w * 2 + 1) * 512 + lane * 8,
               &Vl[cur ^ 1][(w * 2 + 1) * 512]);
    }

    bf16x8 kf[4][2], vf[4][2];
#pragma unroll
    for (int i = 0; i < 4; i++) {
      kf[i][0] = *(const bf16x8*)&Ks[cur][i * 16 + l16][quad * 8];
      kf[i][1] = *(const bf16x8*)&Ks[cur][i * 16 + l16][32 + quad * 8];
      int D4 = (i * 16 + l16) * 4;
      bf16x4 a0 = *(const bf16x4*)&Vl[cur][quad * 512 + D4];
      bf16x4 a1 = *(const bf16x4*)&Vl[cur][quad * 512 + D4 + 256];
      bf16x4 a2 = *(const bf16x4*)&Vl[cur][quad * 512 + D4 + 2048];
      bf16x4 a3 = *(const bf16x4*)&Vl[cur][quad * 512 + D4 + 2048 + 256];
      vf[i][0] = __builtin_shufflevector(a0, a1, 0, 1, 2, 3, 4, 5, 6, 7);
      vf[i][1] = __builtin_shufflevector(a2, a3, 0, 1, 2, 3, 4, 5, 6, 7);
    }

    bf16x8 bp[2][2];
#pragma unroll
    for (int g = 0; g < 4; g++) {
      const int sl = g & 1;
#pragma unroll
      for (int i = 0; i < 4; i++) {
        f32x4 st = f32x4{0.f, 0.f, 0.f, 0.f};
        st = __builtin_amdgcn_mfma_f32_16x16x32_bf16(kf[i][0], aq[g][0], st, 0, 0, 0);
        st = __builtin_amdgcn_mfma_f32_16x16x32_bf16(kf[i][1], aq[g][1], st, 0, 0, 0);
        bf16x4 pk;
#pragma unroll
        for (int r = 0; r < 4; r++) {
          float p = __expf(st[r] - 8.0f);
          ls[g] += p;
          pk[r] = (bf16)p;
        }
        *(bf16x4*)&Ps[w][sl][l16][i * 16 + quad * 4] = pk;
      }
      bp[sl][0] = *(const bf16x8*)&Ps[w][sl][l16][quad * 8];
      bp[sl][1] = *(const bf16x8*)&Ps[w][sl][l16][32 + quad * 8];
      if (g > 0) {
        const int pg = (g - 1) & 1;
#pragma unroll
        for (int i = 0; i < 4; i++) {
          o[g - 1][i] = __builtin_amdgcn_mfma_f32_16x16x32_bf16(vf[i][0], bp[pg][0], o[g - 1][i], 0, 0, 0);
          o[g - 1][i] = __builtin_amdgcn_mfma_f32_16x16x32_bf16(vf[i][1], bp[pg][1], o[g - 1][i], 0, 0, 0);
        }
      }
    }
#pragma unroll
    for (int i = 0; i < 4; i++) {
      o[3][i] = __builtin_amdgcn_mfma_f32_16x16x32_bf16(vf[i][0], bp[1][0], o[3][i], 0, 0, 0);
      o[3][i] = __builtin_amdgcn_mfma_f32_16x16x32_bf16(vf[i][1], bp[1][1], o[3][i], 0, 0, 0);
    }

    if (pf) {
      asm volatile("s_waitcnt vmcnt(0)" ::: "memory");
      *(bf16x8*)&Ks[cur ^ 1][sr][sc] = kr0;
      *(bf16x8*)&Ks[cur ^ 1][sr + 32][sc] = kr1;
    }
    asm volatile("s_waitcnt lgkmcnt(0)" ::: "memory");
    BAR();
  }

#pragma unroll
  for (int g = 0; g < 4; g++) {
    float l = ls[g];
    l += __shfl_xor(l, 16, 64);
    l += __shfl_xor(l, 32, 64);
    float inv = 1.0f / l;
#pragma unroll
    for (int i = 0; i < 4; i++) {
      bf16x4 ov;
#pragma unroll
      for (int r = 0; r < 4; r++) ov[r] = (bf16)(o[g][i][r] * inv);
      *(bf16x4*)(qb + qrow[g] + i * 16 + quad * 4) = ov;
    }
  }
}

// ---------------------------------------------------------------- launcher
extern "C" void kernel_launch(void* const* d_in, const int* in_sizes, int n_in,
                              void* d_out, int out_size, void* d_ws, size_t ws_size,
                              hipStream_t stream) {
  (void)in_sizes; (void)n_in; (void)out_size; (void)ws_size;
  const float* x     = (const float*)d_in[0];
  const float* w_qkv = (const float*)d_in[1];
  const float* b_qkv = (const float*)d_in[2];
  const float* q_g   = (const float*)d_in[3];
  const float* k_g   = (const float*)d_in[4];
  const float* w_out = (const float*)d_in[5];
  const float* b_out = (const float*)d_in[6];
  float* out = (float*)d_out;

  char* ws = (char*)d_ws;
  bf16* wqkvT = (bf16*)ws; ws += (long)3072 * 1024 * 2;      // 6 MB
  bf16* woT   = (bf16*)ws; ws += (long)1024 * 1024 * 2;      // 2 MB
  bf16* xb    = (bf16*)ws; ws += (long)8192 * 1024 * 2;      // 16 MB
  bf16* qb    = (bf16*)ws; ws += (long)128 * 1024 * 64 * 2;  // 16 MB (q, then attention O)
  bf16* kb    = (bf16*)ws; ws += (long)128 * 1024 * 64 * 2;  // 16 MB
  bf16* v4    = (bf16*)ws; ws += (long)128 * 64 * 1024 * 2;  // 16 MB   (total 72 MB)

  prep_k<<<8192, 256, 0, stream>>>(x, xb, w_qkv, wqkvT, w_out, woT);
  gemm256<<<dim3(3072 / 256, 8192 / 128), 512, 0, stream>>>(xb, wqkvT, b_qkv, 1024,
                                                            qb, kb, v4, q_g, k_g);
  attn_k<<<dim3(4, 128), 256, 0, stream>>>(qb, kb, v4);
  gemm_bt1<<<dim3(1024 / 128, 8192 / 128), 256, 0, stream>>>(qb, woT, b_out,
                                                             1024, 1024, out);
}